// Round 4
// baseline (1864.455 us; speedup 1.0000x reference)
//
#include <hip/hip_runtime.h>
#include <math.h>

#define B_ 8192
#define L_ 49
#define C_ 512
#define R_ 128

typedef short   bf16x8 __attribute__((ext_vector_type(8)));
typedef unsigned short u16x8 __attribute__((ext_vector_type(8)));
typedef float   f32x4  __attribute__((ext_vector_type(4)));

// ws layout (ushort elements)
#define WS_LWB   0           // [128][512]  l_reduce_w bf16
#define WS_WB3   65536       // [9][64][64] w3 tap-major bf16
#define WS_WB5   102400      // [25][64][64] w5 tap-major bf16
#define WS_GWB   204800      // [128][512]  g_reduce_w bf16
#define WS_CWB   270336      // [512][128]  channel_w bf16

// shared memory layout (bytes), total 40464 -> 4 blocks/CU
#define SM_XB    0           // ush[49][256] swizzled, 25088 | overlay after P3b:
#define SM_PART  0           //   float part[49][65] = 12740
#define SM_CA    12752       //   float ca[512] = 2048 (16B aligned)
#define SM_XLB   25088       // ush[50][128] swizzled, 12800 | overlay during P1/P2:
#define SM_MAXB  25088       //   bf16 maxb[8][256] = 4096
#define SM_SUMF  29184       //   f32 sumf[8][256]  = 8192
#define SM_GA    37888       // bf16 ga[2][256] = 1024 (per-half A rows: max, avg)
#define SM_G     38912       // f32 g[2][128] = 1024
#define SM_SPACC 39936       // f32[64]
#define SM_SP    40192       // f32[64]
#define SM_GDOT  40448       // f32[4]
#define SM_TOT   40464

__device__ __forceinline__ float bf2f(unsigned short u) {
    union { float f; unsigned int i; } v; v.i = ((unsigned int)u) << 16; return v.f;
}
__device__ __forceinline__ unsigned short f2bf(float f) {
    union { float f; unsigned int i; } v; v.f = f;
    unsigned int r = v.i + 0x7fffu + ((v.i >> 16) & 1u);
    return (unsigned short)(r >> 16);
}
__device__ __forceinline__ float star_relu(float x, float sc, float bi) {
    float r = fmaxf(x, 0.f);
    return sc * r * r + bi;
}
__device__ __forceinline__ float sigmoidf_(float x) {
    return 1.f / (1.f + __expf(-x));
}

// ---------------- pre-pass: convert weights to bf16 into ws ----------------
__global__ void cvt_weights(const float* __restrict__ lw, const float* __restrict__ w3,
                            const float* __restrict__ w5, const float* __restrict__ gw,
                            const float* __restrict__ cw, unsigned short* __restrict__ ws)
{
    int t = blockIdx.x * blockDim.x + threadIdx.x;
    int stride = gridDim.x * blockDim.x;
    for (int i = t; i < 65536; i += stride) ws[WS_LWB + i] = f2bf(lw[i]);
    for (int i = t; i < 65536; i += stride) ws[WS_GWB + i] = f2bf(gw[i]);
    for (int i = t; i < 65536; i += stride) ws[WS_CWB + i] = f2bf(cw[i]);
    for (int i = t; i < 36864; i += stride) {             // [tap][o][ic] <- w3[o][ic][tap]
        int tap = i >> 12, rem = i & 4095;
        ws[WS_WB3 + i] = f2bf(w3[rem * 9 + tap]);
    }
    for (int i = t; i < 102400; i += stride) {            // [tap][o][ic] <- w5[o][ic][tap]
        int tap = i / 4096, rem = i % 4096;
        ws[WS_WB5 + i] = f2bf(w5[rem * 25 + tap]);
    }
}

// ---------------- conv tap-GEMM body. Invalid taps read zeroed row 49. ----------------
template <int NTAP, int KD, int PAD, int COLBASE, int T0, int T1>
__device__ __forceinline__ void conv_mfma(const unsigned short* __restrict__ s_xlb,
                                          const unsigned short* __restrict__ wtb,
                                          int m16, int kg, int oc, f32x4 C[4])
{
    int lp_[4], i_[4], j_[4];
    #pragma unroll
    for (int mf = 0; mf < 4; ++mf) {
        lp_[mf] = mf * 16 + m16;
        i_[mf] = lp_[mf] / 7;
        j_[mf] = lp_[mf] % 7;
    }
    #pragma unroll
    for (int tap = T0; tap < T1; ++tap) {
        const int dy = tap / KD - PAD, dx = tap % KD - PAD;
        int lc[4];
        #pragma unroll
        for (int mf = 0; mf < 4; ++mf) {
            int ii = i_[mf] + dy, jj = j_[mf] + dx;
            bool v = (lp_[mf] < 49) & (ii >= 0) & (ii < 7) & (jj >= 0) & (jj < 7);
            lc[mf] = v ? (ii * 7 + jj) : 49;              // row 49 is all zeros
        }
        #pragma unroll
        for (int ks = 0; ks < 2; ++ks) {
            bf16x8 bb = *(const bf16x8*)(wtb + tap * 4096 + oc * 64 + ks * 32 + kg * 8);
            #pragma unroll
            for (int mf = 0; mf < 4; ++mf) {
                int chunk = ((COLBASE >> 3) + ks * 4 + kg) ^ (lc[mf] & 7);
                bf16x8 a = *(const bf16x8*)&s_xlb[lc[mf] * 128 + chunk * 8];
                C[mf] = __builtin_amdgcn_mfma_f32_16x16x32_bf16(a, bb, C[mf], 0, 0, 0);
            }
        }
    }
}

// ---------------- main fused kernel: one block per batch, 4 blocks/CU ----------------
__global__ __launch_bounds__(512, 8)
void mafn_fused(const float* __restrict__ x,
                const float* __restrict__ b3, const float* __restrict__ b5,
                const float* __restrict__ cb, const float* __restrict__ sw,
                const float* __restrict__ sb, const float* __restrict__ ssc,
                const float* __restrict__ sbi,
                const unsigned short* __restrict__ ws,
                float* __restrict__ out)
{
    __shared__ __align__(16) unsigned char smem[SM_TOT];
    unsigned short* s_xb   = (unsigned short*)(smem + SM_XB);
    float*          s_part = (float*)(smem + SM_PART);
    float*          s_ca   = (float*)(smem + SM_CA);
    unsigned short* s_xlb  = (unsigned short*)(smem + SM_XLB);
    unsigned short* s_maxb = (unsigned short*)(smem + SM_MAXB);
    float*          s_sumf = (float*)(smem + SM_SUMF);
    unsigned short* s_ga   = (unsigned short*)(smem + SM_GA);
    float*          s_g    = (float*)(smem + SM_G);
    float*          s_spacc= (float*)(smem + SM_SPACC);
    float*          s_sp   = (float*)(smem + SM_SP);
    float*          s_gdot = (float*)(smem + SM_GDOT);

    const int b = blockIdx.x, t = threadIdx.x;
    const int wv = t >> 6, ln = t & 63;
    const int m16 = ln & 15, kg = ln >> 4;
    const float scale = ssc[0], sbias = sbi[0];

    const unsigned short* lwb = ws + WS_LWB;
    const unsigned short* wb3 = ws + WS_WB3;
    const unsigned short* wb5 = ws + WS_WB5;
    const unsigned short* gwb = ws + WS_GWB;
    const unsigned short* cwb = ws + WS_CWB;

    f32x4 accA[4][2];    // x_l accumulators (waves 0-3)
    f32x4 accG[2];       // g accumulators (waves 4-7)
    {
        const f32x4 z = {0.f, 0.f, 0.f, 0.f};
        #pragma unroll
        for (int mf = 0; mf < 4; ++mf) { accA[mf][0] = z; accA[mf][1] = z; }
        accG[0] = z; accG[1] = z;
    }

    const int l0 = wv * 6;
    const int nl = (wv < 7) ? 6 : 7;      // rows 42..48 for wave 7

    // ================= K-split halves: P1 load / P2 reduce / P3 GEMMs =================
    #pragma unroll 1
    for (int h = 0; h < 2; ++h) {
        // ---- P1: load x half (f32), partials, bf16 -> swizzled LDS ----
        {
            const float4* x4 = (const float4*)(x + (size_t)b * (L_ * C_)) + h * 64;
            float4 mx = {-3.4e38f, -3.4e38f, -3.4e38f, -3.4e38f};
            float4 sm = {0.f, 0.f, 0.f, 0.f};
            for (int li = 0; li < nl; ++li) {
                int l = l0 + li;
                float4 v = x4[l * 128 + ln];
                mx.x = fmaxf(mx.x, v.x); mx.y = fmaxf(mx.y, v.y);
                mx.z = fmaxf(mx.z, v.z); mx.w = fmaxf(mx.w, v.w);
                sm.x += v.x; sm.y += v.y; sm.z += v.z; sm.w += v.w;
                ushort4 p;
                p.x = f2bf(v.x); p.y = f2bf(v.y); p.z = f2bf(v.z); p.w = f2bf(v.w);
                int chunk = (ln >> 1) ^ (l & 7);
                *(ushort4*)&s_xb[l * 256 + chunk * 8 + (ln & 1) * 4] = p;
            }
            ushort4 pm;
            pm.x = f2bf(mx.x); pm.y = f2bf(mx.y); pm.z = f2bf(mx.z); pm.w = f2bf(mx.w);
            *(ushort4*)&s_maxb[wv * 256 + ln * 4] = pm;
            *(float4*)&s_sumf[wv * 256 + ln * 4] = sm;
        }
        __syncthreads();

        // ---- P2: finalize max/avg for this half -> bf16 A rows ----
        {
            if (t < 256) {
                int c = t;
                float m = bf2f(s_maxb[c]);
                #pragma unroll
                for (int i = 1; i < 8; ++i) m = fmaxf(m, bf2f(s_maxb[i * 256 + c]));
                s_ga[c] = f2bf(m);                       // exact: m already a bf16 value
            } else {
                int c = t - 256;
                float s = 0.f;
                #pragma unroll
                for (int i = 0; i < 8; ++i) s += s_sumf[i * 256 + c];
                s_ga[256 + c] = f2bf(s * (1.f / 49.f));
            }
            if (h == 0 && t < 64) s_spacc[t] = 0.f;
        }
        __syncthreads();

        // ---- P3: waves 0-3: x_l MFMA  ||  waves 4-7: g MFMA ----
        if (wv < 4) {
            int rowA[4];
            #pragma unroll
            for (int mf = 0; mf < 4; ++mf) rowA[mf] = min(mf * 16 + m16, 48);
            #pragma unroll 4
            for (int ks = 0; ks < 8; ++ks) {
                bf16x8 a[4];
                #pragma unroll
                for (int mf = 0; mf < 4; ++mf) {
                    int chunk = (ks * 4 + kg) ^ (rowA[mf] & 7);
                    a[mf] = *(const bf16x8*)&s_xb[rowA[mf] * 256 + chunk * 8];
                }
                #pragma unroll
                for (int bf = 0; bf < 2; ++bf) {
                    int n = wv * 32 + bf * 16 + m16;
                    bf16x8 bb = *(const bf16x8*)(lwb + n * 512 + h * 256 + ks * 32 + kg * 8);
                    #pragma unroll
                    for (int mf = 0; mf < 4; ++mf)
                        accA[mf][bf] = __builtin_amdgcn_mfma_f32_16x16x32_bf16(a[mf], bb, accA[mf][bf], 0, 0, 0);
                }
            }
        } else {
            const bf16x8 zz = {0,0,0,0,0,0,0,0};
            #pragma unroll 4
            for (int ks = 0; ks < 8; ++ks) {
                bf16x8 a = (m16 < 2) ? *(const bf16x8*)&s_ga[m16 * 256 + ks * 32 + kg * 8] : zz;
                #pragma unroll
                for (int bf = 0; bf < 2; ++bf) {
                    int n = (wv - 4) * 32 + bf * 16 + m16;
                    bf16x8 bb = *(const bf16x8*)(gwb + n * 512 + h * 256 + ks * 32 + kg * 8);
                    accG[bf] = __builtin_amdgcn_mfma_f32_16x16x32_bf16(a, bb, accG[bf], 0, 0, 0);
                }
            }
        }
        __syncthreads();
    }

    // ---- P4a: waves 0-3: store x_l bf16 (swizzled) || waves 4-7: store g ----
    if (wv < 4) {
        if (t < 64) ((unsigned int*)(s_xlb + 49 * 128))[t] = 0;   // zero row 49
        #pragma unroll
        for (int mf = 0; mf < 4; ++mf) {
            #pragma unroll
            for (int bf = 0; bf < 2; ++bf) {
                int n = wv * 32 + bf * 16 + m16;
                #pragma unroll
                for (int rg = 0; rg < 4; ++rg) {
                    int lp = mf * 16 + kg * 4 + rg;
                    if (lp < 49) {
                        int idx = lp * 128 + ((((n >> 3) ^ (lp & 7)) << 3) + (n & 7));
                        s_xlb[idx] = f2bf(accA[mf][bf][rg]);
                    }
                }
            }
        }
    } else if (kg == 0) {
        #pragma unroll
        for (int bf = 0; bf < 2; ++bf) {
            int n = (wv - 4) * 32 + bf * 16 + m16;
            s_g[n]       = star_relu(accG[bf][0], scale, sbias);   // row 0 = max -> g1
            s_g[128 + n] = star_relu(accG[bf][1], scale, sbias);   // row 1 = avg -> g2
        }
    }
    __syncthreads();

    // ---- P4b: c_aggr (all 512 threads, 1 channel each) + gdot (wave 7) ----
    {
        int c = t;
        const unsigned short* wrow = cwb + c * 128;
        float a0 = 0.f, a1 = 0.f;
        #pragma unroll 4
        for (int r8 = 0; r8 < 16; ++r8) {
            u16x8 w = *(const u16x8*)(wrow + r8 * 8);
            float p = 0.f;
            #pragma unroll
            for (int k = 0; k < 8; ++k)
                p += bf2f(w[k]) * (s_g[r8 * 8 + k] + s_g[128 + r8 * 8 + k]);
            if (r8 & 1) a1 += p; else a0 += p;
        }
        s_ca[c] = sigmoidf_(a0 + a1 + 2.f * cb[c]);
        if (wv == 7) {
            float p = s_g[ln] * sw[128 + ln] + s_g[128 + ln] * sw[256 + ln]
                    + s_g[ln + 64] * sw[128 + ln + 64] + s_g[128 + ln + 64] * sw[256 + ln + 64];
            #pragma unroll
            for (int off = 32; off > 0; off >>= 1) p += __shfl_xor(p, off);
            if (ln == 0) s_gdot[0] = p;
        }
    }
    __syncthreads();

    // ---- P5a: balanced convs (136 MFMA per wave) ----
    const int f_ = wv & 3;
    const int oc_ = f_ * 16 + m16;
    f32x4 C[4];
    {
        const f32x4 z = {0.f, 0.f, 0.f, 0.f};
        #pragma unroll
        for (int mf = 0; mf < 4; ++mf) C[mf] = z;

        if (wv < 4) {
            conv_mfma<25, 5, 2, 64, 0, 17>(s_xlb, wb5, m16, kg, oc_, C);   // conv5 taps 0..16
        } else {
            f32x4 Cp[4];
            #pragma unroll
            for (int mf = 0; mf < 4; ++mf) Cp[mf] = z;
            conv_mfma<25, 5, 2, 64, 17, 25>(s_xlb, wb5, m16, kg, oc_, Cp); // conv5 taps 17..24
            #pragma unroll
            for (int mf = 0; mf < 4; ++mf) {
                #pragma unroll
                for (int rg = 0; rg < 4; ++rg) {
                    int lp = mf * 16 + kg * 4 + rg;
                    if (lp < 49) s_part[lp * 65 + oc_] = Cp[mf][rg];
                }
            }
            conv_mfma<9, 3, 1, 0, 0, 9>(s_xlb, wb3, m16, kg, oc_, C);      // conv3 full
        }
    }
    __syncthreads();

    // ---- P5b: merge partials; star_relu + sw-dot epilogue ----
    {
        if (wv < 4) {
            #pragma unroll
            for (int mf = 0; mf < 4; ++mf) {
                #pragma unroll
                for (int rg = 0; rg < 4; ++rg) {
                    int lp = mf * 16 + kg * 4 + rg;
                    if (lp < 49) C[mf][rg] += s_part[lp * 65 + oc_];
                }
            }
        }
        const bool is5 = (wv < 4);
        const int ch = is5 ? 64 + oc_ : oc_;
        const float bias = is5 ? b5[oc_] : b3[oc_];
        const float sww = sw[ch];
        #pragma unroll
        for (int mf = 0; mf < 4; ++mf) {
            #pragma unroll
            for (int rg = 0; rg < 4; ++rg) {
                int lp = mf * 16 + kg * 4 + rg;
                float v = (lp < 49) ? star_relu(C[mf][rg] + bias, scale, sbias) * sww : 0.f;
                v += __shfl_xor(v, 1);
                v += __shfl_xor(v, 2);
                v += __shfl_xor(v, 4);
                v += __shfl_xor(v, 8);
                if (m16 == 0 && lp < 49) atomicAdd(&s_spacc[lp], v);
            }
        }
    }
    __syncthreads();

    // ---- P6: spatial gate ----
    if (t < 49) s_sp[t] = sigmoidf_(s_spacc[t] + s_gdot[0] + sb[0]);
    __syncthreads();

    // ---- P7: out = x * ca[c] * sp[l] (x re-read f32, L2-hot) ----
    {
        const float4* x4 = (const float4*)(x + (size_t)b * (L_ * C_));
        float4* o4 = (float4*)(out + (size_t)b * (L_ * C_));
        const float4* ca4 = (const float4*)s_ca;
        for (int i = t; i < 49 * 128; i += 512) {
            int l = i >> 7, c4 = i & 127;
            float4 xv = x4[i];
            float g = s_sp[l];
            float4 cv = ca4[c4];
            float4 ov;
            ov.x = xv.x * cv.x * g;
            ov.y = xv.y * cv.y * g;
            ov.z = xv.z * cv.z * g;
            ov.w = xv.w * cv.w * g;
            o4[i] = ov;
        }
    }
}

extern "C" void kernel_launch(void* const* d_in, const int* in_sizes, int n_in,
                              void* d_out, int out_size, void* d_ws, size_t ws_size,
                              hipStream_t stream) {
    (void)in_sizes; (void)n_in; (void)ws_size; (void)out_size;
    const float* x    = (const float*)d_in[0];
    const float* g_w  = (const float*)d_in[1];
    const float* l_w  = (const float*)d_in[2];
    const float* w3   = (const float*)d_in[3];
    const float* b3   = (const float*)d_in[4];
    const float* w5   = (const float*)d_in[5];
    const float* b5   = (const float*)d_in[6];
    const float* cw   = (const float*)d_in[7];
    const float* cb   = (const float*)d_in[8];
    const float* sw   = (const float*)d_in[9];
    const float* sb   = (const float*)d_in[10];
    const float* ssc  = (const float*)d_in[11];
    const float* sbi  = (const float*)d_in[12];
    float* outp = (float*)d_out;
    unsigned short* ws = (unsigned short*)d_ws;

    cvt_weights<<<dim3(512), dim3(256), 0, stream>>>(l_w, w3, w5, g_w, cw, ws);
    mafn_fused<<<dim3(B_), dim3(512), 0, stream>>>(
        x, b3, b5, cb, sw, sb, ssc, sbi, ws, outp);
}

// Round 5
// 939.955 us; speedup vs baseline: 1.9836x; 1.9836x over previous
//
#include <hip/hip_runtime.h>
#include <math.h>

#define B_ 8192
#define L_ 49
#define C_ 512
#define R_ 128

typedef short   bf16x8 __attribute__((ext_vector_type(8)));
typedef unsigned short u16x8 __attribute__((ext_vector_type(8)));
typedef float   f32x4  __attribute__((ext_vector_type(4)));

// ws layout (ushort elements)
#define WS_LWB   0           // [128][512]  l_reduce_w bf16
#define WS_WB3   65536       // [9][64][64] w3 tap-major bf16
#define WS_WB5   102400      // [25][64][64] w5 tap-major bf16
#define WS_GWB   204800      // [128][512]  g_reduce_w bf16
#define WS_CWB   270336      // [512][128]  channel_w bf16

// shared memory layout (bytes), total 40464 -> 4 blocks/CU
#define SM_XB    0           // ush[49][256] swizzled, 25088 | overlay after P3:
#define SM_PART  0           //   float part[49][65] = 12740
#define SM_CA    12752       //   float ca[512] = 2048
#define SM_XLB   25088       // ush[50][128] swizzled, 12800 | overlay during P1/P2:
#define SM_MAXB  25088       //   bf16 maxb[8][256] = 4096
#define SM_SUMF  29184       //   f32 sumf[8][256]  = 8192
#define SM_GA    37888       // bf16 ga[2][256] = 1024
#define SM_G     38912       // f32 g[2][128] = 1024
#define SM_SPACC 39936       // f32[64]
#define SM_SP    40192       // f32[64]
#define SM_GDOT  40448       // f32[4]
#define SM_TOT   40464

__device__ __forceinline__ float bf2f(unsigned short u) {
    union { float f; unsigned int i; } v; v.i = ((unsigned int)u) << 16; return v.f;
}
__device__ __forceinline__ unsigned short f2bf(float f) {
    union { float f; unsigned int i; } v; v.f = f;
    unsigned int r = v.i + 0x7fffu + ((v.i >> 16) & 1u);
    return (unsigned short)(r >> 16);
}
__device__ __forceinline__ float star_relu(float x, float sc, float bi) {
    float r = fmaxf(x, 0.f);
    return sc * r * r + bi;
}
__device__ __forceinline__ float sigmoidf_(float x) {
    return 1.f / (1.f + __expf(-x));
}

// ---------------- pre-pass: convert weights to bf16 into ws ----------------
__global__ void cvt_weights(const float* __restrict__ lw, const float* __restrict__ w3,
                            const float* __restrict__ w5, const float* __restrict__ gw,
                            const float* __restrict__ cw, unsigned short* __restrict__ ws)
{
    int t = blockIdx.x * blockDim.x + threadIdx.x;
    int stride = gridDim.x * blockDim.x;
    for (int i = t; i < 65536; i += stride) ws[WS_LWB + i] = f2bf(lw[i]);
    for (int i = t; i < 65536; i += stride) ws[WS_GWB + i] = f2bf(gw[i]);
    for (int i = t; i < 65536; i += stride) ws[WS_CWB + i] = f2bf(cw[i]);
    for (int i = t; i < 36864; i += stride) {             // [tap][o][ic] <- w3[o][ic][tap]
        int tap = i >> 12, rem = i & 4095;
        ws[WS_WB3 + i] = f2bf(w3[rem * 9 + tap]);
    }
    for (int i = t; i < 102400; i += stride) {            // [tap][o][ic] <- w5[o][ic][tap]
        int tap = i / 4096, rem = i % 4096;
        ws[WS_WB5 + i] = f2bf(w5[rem * 25 + tap]);
    }
}

// ---------------- conv tap-GEMM body. Invalid taps read zeroed row 49. ----------------
template <int NTAP, int KD, int PAD, int COLBASE, int T0, int T1>
__device__ __forceinline__ void conv_mfma(const unsigned short* __restrict__ s_xlb,
                                          const unsigned short* __restrict__ wtb,
                                          int m16, int kg, int oc, f32x4 C[4])
{
    int lp_[4], i_[4], j_[4];
    #pragma unroll
    for (int mf = 0; mf < 4; ++mf) {
        lp_[mf] = mf * 16 + m16;
        i_[mf] = lp_[mf] / 7;
        j_[mf] = lp_[mf] % 7;
    }
    #pragma unroll
    for (int tap = T0; tap < T1; ++tap) {
        const int dy = tap / KD - PAD, dx = tap % KD - PAD;
        int lc[4];
        #pragma unroll
        for (int mf = 0; mf < 4; ++mf) {
            int ii = i_[mf] + dy, jj = j_[mf] + dx;
            bool v = (lp_[mf] < 49) & (ii >= 0) & (ii < 7) & (jj >= 0) & (jj < 7);
            lc[mf] = v ? (ii * 7 + jj) : 49;              // row 49 is all zeros
        }
        #pragma unroll
        for (int ks = 0; ks < 2; ++ks) {
            bf16x8 bb = *(const bf16x8*)(wtb + tap * 4096 + oc * 64 + ks * 32 + kg * 8);
            #pragma unroll
            for (int mf = 0; mf < 4; ++mf) {
                int chunk = ((COLBASE >> 3) + ks * 4 + kg) ^ (lc[mf] & 7);
                bf16x8 a = *(const bf16x8*)&s_xlb[lc[mf] * 128 + chunk * 8];
                C[mf] = __builtin_amdgcn_mfma_f32_16x16x32_bf16(a, bb, C[mf], 0, 0, 0);
            }
        }
    }
}

// ---------------- main fused kernel: one block per batch, target 4 blocks/CU ----------------
__global__ __launch_bounds__(512, 4)
void mafn_fused(const float* __restrict__ x,
                const float* __restrict__ b3, const float* __restrict__ b5,
                const float* __restrict__ cb, const float* __restrict__ sw,
                const float* __restrict__ sb, const float* __restrict__ ssc,
                const float* __restrict__ sbi,
                const unsigned short* __restrict__ ws,
                float* __restrict__ out)
{
    __shared__ __align__(16) unsigned char smem[SM_TOT];
    unsigned short* s_xb   = (unsigned short*)(smem + SM_XB);
    float*          s_part = (float*)(smem + SM_PART);
    float*          s_ca   = (float*)(smem + SM_CA);
    unsigned short* s_xlb  = (unsigned short*)(smem + SM_XLB);
    unsigned short* s_maxb = (unsigned short*)(smem + SM_MAXB);
    float*          s_sumf = (float*)(smem + SM_SUMF);
    unsigned short* s_ga   = (unsigned short*)(smem + SM_GA);
    float*          s_g    = (float*)(smem + SM_G);
    float*          s_spacc= (float*)(smem + SM_SPACC);
    float*          s_sp   = (float*)(smem + SM_SP);
    float*          s_gdot = (float*)(smem + SM_GDOT);

    const int b = blockIdx.x, t = threadIdx.x;
    const int wv = t >> 6, ln = t & 63;
    const int m16 = ln & 15, kg = ln >> 4;
    const float scale = ssc[0], sbias = sbi[0];

    const unsigned short* lwb = ws + WS_LWB;
    const unsigned short* wb3 = ws + WS_WB3;
    const unsigned short* wb5 = ws + WS_WB5;
    const unsigned short* gwb = ws + WS_GWB;
    const unsigned short* cwb = ws + WS_CWB;

    f32x4 accA[4];       // x_l accumulators: this wave's n-fragment (n = wv*16+m16)
    f32x4 accG;          // g accumulator: this wave's n-fragment
    {
        const f32x4 z = {0.f, 0.f, 0.f, 0.f};
        #pragma unroll
        for (int mf = 0; mf < 4; ++mf) accA[mf] = z;
        accG = z;
    }

    const int l0 = wv * 6;
    const int nl = (wv < 7) ? 6 : 7;      // rows 42..48 for wave 7

    // ================= K-split halves: P1 load / P2 reduce / P3 GEMMs =================
    #pragma unroll 1
    for (int h = 0; h < 2; ++h) {
        // ---- P1: load x half (f32), partials, bf16 -> swizzled LDS ----
        {
            const float4* x4 = (const float4*)(x + (size_t)b * (L_ * C_)) + h * 64;
            float4 mx = {-3.4e38f, -3.4e38f, -3.4e38f, -3.4e38f};
            float4 sm = {0.f, 0.f, 0.f, 0.f};
            for (int li = 0; li < nl; ++li) {
                int l = l0 + li;
                float4 v = x4[l * 128 + ln];
                mx.x = fmaxf(mx.x, v.x); mx.y = fmaxf(mx.y, v.y);
                mx.z = fmaxf(mx.z, v.z); mx.w = fmaxf(mx.w, v.w);
                sm.x += v.x; sm.y += v.y; sm.z += v.z; sm.w += v.w;
                ushort4 p;
                p.x = f2bf(v.x); p.y = f2bf(v.y); p.z = f2bf(v.z); p.w = f2bf(v.w);
                int chunk = (ln >> 1) ^ (l & 7);
                *(ushort4*)&s_xb[l * 256 + chunk * 8 + (ln & 1) * 4] = p;
            }
            ushort4 pm;
            pm.x = f2bf(mx.x); pm.y = f2bf(mx.y); pm.z = f2bf(mx.z); pm.w = f2bf(mx.w);
            *(ushort4*)&s_maxb[wv * 256 + ln * 4] = pm;
            *(float4*)&s_sumf[wv * 256 + ln * 4] = sm;
        }
        __syncthreads();

        // ---- P2: finalize max/avg for this half -> bf16 A rows ----
        {
            if (t < 256) {
                int c = t;
                float m = bf2f(s_maxb[c]);
                #pragma unroll
                for (int i = 1; i < 8; ++i) m = fmaxf(m, bf2f(s_maxb[i * 256 + c]));
                s_ga[c] = f2bf(m);                       // exact: m already a bf16 value
            } else {
                int c = t - 256;
                float s = 0.f;
                #pragma unroll
                for (int i = 0; i < 8; ++i) s += s_sumf[i * 256 + c];
                s_ga[256 + c] = f2bf(s * (1.f / 49.f));
            }
            if (h == 0 && t < 64) s_spacc[t] = 0.f;
        }
        __syncthreads();

        // ---- P3: all 8 waves: x_l MFMA (1 n-frag each), then g MFMA (1 n-frag each) ----
        {
            int rowA[4];
            #pragma unroll
            for (int mf = 0; mf < 4; ++mf) rowA[mf] = min(mf * 16 + m16, 48);
            const int n = wv * 16 + m16;
            #pragma unroll 2
            for (int ks = 0; ks < 8; ++ks) {
                bf16x8 bb = *(const bf16x8*)(lwb + n * 512 + h * 256 + ks * 32 + kg * 8);
                #pragma unroll
                for (int mf = 0; mf < 4; ++mf) {
                    int chunk = (ks * 4 + kg) ^ (rowA[mf] & 7);
                    bf16x8 a = *(const bf16x8*)&s_xb[rowA[mf] * 256 + chunk * 8];
                    accA[mf] = __builtin_amdgcn_mfma_f32_16x16x32_bf16(a, bb, accA[mf], 0, 0, 0);
                }
            }
            const bf16x8 zz = {0,0,0,0,0,0,0,0};
            #pragma unroll 4
            for (int ks = 0; ks < 8; ++ks) {
                bf16x8 a = (m16 < 2) ? *(const bf16x8*)&s_ga[m16 * 256 + ks * 32 + kg * 8] : zz;
                bf16x8 bb = *(const bf16x8*)(gwb + n * 512 + h * 256 + ks * 32 + kg * 8);
                accG = __builtin_amdgcn_mfma_f32_16x16x32_bf16(a, bb, accG, 0, 0, 0);
            }
        }
        __syncthreads();
    }

    // ---- P4a: store x_l bf16 (swizzled, all waves) + g (kg==0 lanes) ----
    {
        if (t < 64) ((unsigned int*)(s_xlb + 49 * 128))[t] = 0;   // zero row 49
        const int n = wv * 16 + m16;
        #pragma unroll
        for (int mf = 0; mf < 4; ++mf) {
            #pragma unroll
            for (int rg = 0; rg < 4; ++rg) {
                int lp = mf * 16 + kg * 4 + rg;
                if (lp < 49) {
                    int idx = lp * 128 + ((((n >> 3) ^ (lp & 7)) << 3) + (n & 7));
                    s_xlb[idx] = f2bf(accA[mf][rg]);
                }
            }
        }
        if (kg == 0) {
            s_g[n]       = star_relu(accG[0], scale, sbias);   // row 0 = max -> g1
            s_g[128 + n] = star_relu(accG[1], scale, sbias);   // row 1 = avg -> g2
        }
    }
    __syncthreads();

    // ---- P4b: c_aggr (all 512 threads, 1 channel each) + gdot (wave 7) ----
    {
        int c = t;
        const unsigned short* wrow = cwb + c * 128;
        float a0 = 0.f, a1 = 0.f;
        #pragma unroll 4
        for (int r8 = 0; r8 < 16; ++r8) {
            u16x8 w = *(const u16x8*)(wrow + r8 * 8);
            float p = 0.f;
            #pragma unroll
            for (int k = 0; k < 8; ++k)
                p += bf2f(w[k]) * (s_g[r8 * 8 + k] + s_g[128 + r8 * 8 + k]);
            if (r8 & 1) a1 += p; else a0 += p;
        }
        s_ca[c] = sigmoidf_(a0 + a1 + 2.f * cb[c]);
        if (wv == 7) {
            float p = s_g[ln] * sw[128 + ln] + s_g[128 + ln] * sw[256 + ln]
                    + s_g[ln + 64] * sw[128 + ln + 64] + s_g[128 + ln + 64] * sw[256 + ln + 64];
            #pragma unroll
            for (int off = 32; off > 0; off >>= 1) p += __shfl_xor(p, off);
            if (ln == 0) s_gdot[0] = p;
        }
    }
    __syncthreads();

    // ---- P5a: balanced convs (136 MFMA per wave); C reused for partials ----
    const int f_ = wv & 3;
    const int oc_ = f_ * 16 + m16;
    f32x4 C[4];
    {
        const f32x4 z = {0.f, 0.f, 0.f, 0.f};
        #pragma unroll
        for (int mf = 0; mf < 4; ++mf) C[mf] = z;

        if (wv < 4) {
            conv_mfma<25, 5, 2, 64, 0, 17>(s_xlb, wb5, m16, kg, oc_, C);   // conv5 taps 0..16
        } else {
            conv_mfma<25, 5, 2, 64, 17, 25>(s_xlb, wb5, m16, kg, oc_, C);  // conv5 taps 17..24
            #pragma unroll
            for (int mf = 0; mf < 4; ++mf) {
                #pragma unroll
                for (int rg = 0; rg < 4; ++rg) {
                    int lp = mf * 16 + kg * 4 + rg;
                    if (lp < 49) s_part[lp * 65 + oc_] = C[mf][rg];
                }
                C[mf] = z;
            }
            conv_mfma<9, 3, 1, 0, 0, 9>(s_xlb, wb3, m16, kg, oc_, C);      // conv3 full
        }
    }
    __syncthreads();

    // ---- P5b: merge partials; star_relu + sw-dot epilogue ----
    {
        if (wv < 4) {
            #pragma unroll
            for (int mf = 0; mf < 4; ++mf) {
                #pragma unroll
                for (int rg = 0; rg < 4; ++rg) {
                    int lp = mf * 16 + kg * 4 + rg;
                    if (lp < 49) C[mf][rg] += s_part[lp * 65 + oc_];
                }
            }
        }
        const bool is5 = (wv < 4);
        const int ch = is5 ? 64 + oc_ : oc_;
        const float bias = is5 ? b5[oc_] : b3[oc_];
        const float sww = sw[ch];
        #pragma unroll
        for (int mf = 0; mf < 4; ++mf) {
            #pragma unroll
            for (int rg = 0; rg < 4; ++rg) {
                int lp = mf * 16 + kg * 4 + rg;
                float v = (lp < 49) ? star_relu(C[mf][rg] + bias, scale, sbias) * sww : 0.f;
                v += __shfl_xor(v, 1);
                v += __shfl_xor(v, 2);
                v += __shfl_xor(v, 4);
                v += __shfl_xor(v, 8);
                if (m16 == 0 && lp < 49) atomicAdd(&s_spacc[lp], v);
            }
        }
    }
    __syncthreads();

    // ---- P6: spatial gate ----
    if (t < 49) s_sp[t] = sigmoidf_(s_spacc[t] + s_gdot[0] + sb[0]);
    __syncthreads();

    // ---- P7: out = x * ca[c] * sp[l] (x re-read f32, L2-hot) ----
    {
        const float4* x4 = (const float4*)(x + (size_t)b * (L_ * C_));
        float4* o4 = (float4*)(out + (size_t)b * (L_ * C_));
        const float4* ca4 = (const float4*)s_ca;
        for (int i = t; i < 49 * 128; i += 512) {
            int l = i >> 7, c4 = i & 127;
            float4 xv = x4[i];
            float g = s_sp[l];
            float4 cv = ca4[c4];
            float4 ov;
            ov.x = xv.x * cv.x * g;
            ov.y = xv.y * cv.y * g;
            ov.z = xv.z * cv.z * g;
            ov.w = xv.w * cv.w * g;
            o4[i] = ov;
        }
    }
}

extern "C" void kernel_launch(void* const* d_in, const int* in_sizes, int n_in,
                              void* d_out, int out_size, void* d_ws, size_t ws_size,
                              hipStream_t stream) {
    (void)in_sizes; (void)n_in; (void)ws_size; (void)out_size;
    const float* x    = (const float*)d_in[0];
    const float* g_w  = (const float*)d_in[1];
    const float* l_w  = (const float*)d_in[2];
    const float* w3   = (const float*)d_in[3];
    const float* b3   = (const float*)d_in[4];
    const float* w5   = (const float*)d_in[5];
    const float* b5   = (const float*)d_in[6];
    const float* cw   = (const float*)d_in[7];
    const float* cb   = (const float*)d_in[8];
    const float* sw   = (const float*)d_in[9];
    const float* sb   = (const float*)d_in[10];
    const float* ssc  = (const float*)d_in[11];
    const float* sbi  = (const float*)d_in[12];
    float* outp = (float*)d_out;
    unsigned short* ws = (unsigned short*)d_ws;

    cvt_weights<<<dim3(512), dim3(256), 0, stream>>>(l_w, w3, w5, g_w, cw, ws);
    mafn_fused<<<dim3(B_), dim3(512), 0, stream>>>(
        x, b3, b5, cb, sw, sb, ssc, sbi, ws, outp);
}